// Round 6
// baseline (662.741 us; speedup 1.0000x reference)
//
#include <hip/hip_runtime.h>
#include <hip/hip_bf16.h>

#define LRALPHA 0.2f
#define LOG2E 1.4426950408889634f

typedef __attribute__((ext_vector_type(8))) short frag_ab;   // 8 x bf16
typedef __attribute__((ext_vector_type(4))) float frag_cd;   // 4 x f32
typedef float fv2 __attribute__((ext_vector_type(2)));
typedef unsigned int uv4 __attribute__((ext_vector_type(4)));

static __device__ __forceinline__ unsigned short f2bf(float f) {
  __hip_bfloat16 b = __float2bfloat16(f);
  unsigned short u;
  __builtin_memcpy(&u, &b, 2);
  return u;
}

#if __has_builtin(__builtin_amdgcn_exp2f)
#define EXP2F(x) __builtin_amdgcn_exp2f(x)
#else
#define EXP2F(x) exp2f(x)
#endif

// 2 x f32 -> packed 2 x bf16 (RNE), gfx950-native
static __device__ __forceinline__ unsigned cvt_pk_bf16(float lo, float hi) {
  unsigned r;
  asm("v_cvt_pk_bf16_f32 %0, %1, %2" : "=v"(r) : "v"(lo), "v"(hi));
  return r;
}

// Barrier ordering LDS only: lgkmcnt(0) + s_barrier, NO vmcnt drain.
static __device__ __forceinline__ void block_sync_lds() {
  __builtin_amdgcn_sched_barrier(0);
  asm volatile("s_waitcnt lgkmcnt(0)" ::: "memory");
  __builtin_amdgcn_s_barrier();
  __builtin_amdgcn_sched_barrier(0);
}

// 2 elems: w = exp2(lrelu(s1r + s2[j]) - mr), masked by bits 0/1 of mbits.
static __device__ __forceinline__ unsigned make_w2(unsigned mbits, fv2 cv,
                                                   float s1r, float mr, float& zloc) {
  float w[2];
#pragma unroll
  for (int e = 0; e < 2; ++e) {
    float ee = s1r + cv[e];                  // log2 units
    ee = fmaxf(ee, LRALPHA * ee);            // leakyrelu (slope<1)
    float ww = EXP2F(ee - mr);               // <= 1 by construction
    ww = ((mbits >> e) & 1u) ? ww : 0.f;
    zloc += ww;
    w[e] = ww;
  }
  return cvt_pk_bf16(w[0], w[1]);
}

// ---------------- Kernel 0: adj (int32, 256 MB) -> bitmask (8 MB)
// Pure streaming: one dword/lane, __ballot(adj>0) -> one uint64/wave.
// 2048 blocks x 256 thr = 8192 waves; 4-deep unroll keeps ~1KB/wave in flight.
__global__ __launch_bounds__(256) void gat_adjpack(
    const int* __restrict__ adj, unsigned long long* __restrict__ mask) {
  const int lane = threadIdx.x & 63;
  const int wid = (blockIdx.x * 256 + threadIdx.x) >> 6;  // 0..8191
  const int NW = (2048 * 256) >> 6;                       // 8192
  const int NWORDS = (8192 * 8192) / 64;                  // 1,048,576
  for (int w0 = wid * 4; w0 < NWORDS; w0 += NW * 4) {
    int v0 = __builtin_nontemporal_load(&adj[(size_t)(w0 + 0) * 64 + lane]);
    int v1 = __builtin_nontemporal_load(&adj[(size_t)(w0 + 1) * 64 + lane]);
    int v2 = __builtin_nontemporal_load(&adj[(size_t)(w0 + 2) * 64 + lane]);
    int v3 = __builtin_nontemporal_load(&adj[(size_t)(w0 + 3) * 64 + lane]);
    unsigned long long m0 = __ballot(v0 > 0);
    unsigned long long m1 = __ballot(v1 > 0);
    unsigned long long m2 = __ballot(v2 > 0);
    unsigned long long m3 = __ballot(v3 > 0);
    if (lane == 0) {
      mask[w0 + 0] = m0; mask[w0 + 1] = m1;
      mask[w0 + 2] = m2; mask[w0 + 3] = m3;
    }
  }
}

// ---------------- Kernel A: h = X@W (fp32), s1/s2 (pre-scaled by log2 e), hT = bf16(h)^T
__global__ __launch_bounds__(256, 4) void gat_hproj(
    const float* __restrict__ X, const float* __restrict__ W,
    const float* __restrict__ avec,
    float* __restrict__ s1, float* __restrict__ s2,
    unsigned short* __restrict__ hT) {
  const int tid = threadIdx.x;
  const int row0 = blockIdx.x * 16;
  const float* Xb = X + (size_t)row0 * 256;
  const int c = tid;  // output column 0..255

  float acc[16];
#pragma unroll
  for (int r = 0; r < 16; ++r) acc[r] = 0.f;

  for (int k = 0; k < 256; k += 4) {
    const float w0 = W[(k + 0) * 256 + c];
    const float w1 = W[(k + 1) * 256 + c];
    const float w2 = W[(k + 2) * 256 + c];
    const float w3 = W[(k + 3) * 256 + c];
#pragma unroll
    for (int r = 0; r < 16; ++r) {
      acc[r] = fmaf(Xb[r * 256 + k + 0], w0, acc[r]);
      acc[r] = fmaf(Xb[r * 256 + k + 1], w1, acc[r]);
      acc[r] = fmaf(Xb[r * 256 + k + 2], w2, acc[r]);
      acc[r] = fmaf(Xb[r * 256 + k + 3], w3, acc[r]);
    }
  }

  // hT (bf16, [f][j] layout): thread writes 16 contiguous bf16 in row c
  alignas(16) unsigned short hu[16];
#pragma unroll
  for (int r = 0; r < 16; ++r) hu[r] = f2bf(acc[r]);
  uv4* hdst = (uv4*)(hT + (size_t)c * 8192 + row0);
  hdst[0] = *(const uv4*)&hu[0];
  hdst[1] = *(const uv4*)&hu[8];

  // s1/s2: reduce acc[r]*a over 256 threads (=columns); scaled by log2(e).
  const float a1c = avec[c];
  const float a2c = avec[256 + c];
  const int lane = tid & 63, wave = tid >> 6;
  __shared__ float r1[4][16], r2[4][16];
#pragma unroll
  for (int r = 0; r < 16; ++r) {
    float v1 = acc[r] * a1c;
    float v2 = acc[r] * a2c;
#pragma unroll
    for (int off = 32; off > 0; off >>= 1) {
      v1 += __shfl_down(v1, off);
      v2 += __shfl_down(v2, off);
    }
    if (lane == 0) { r1[wave][r] = v1; r2[wave][r] = v2; }
  }
  __syncthreads();
  if (tid < 16) {
    s1[row0 + tid] = (r1[0][tid] + r1[1][tid] + r1[2][tid] + r1[3][tid]) * LOG2E;
    s2[row0 + tid] = (r2[0][tid] + r2[1][tid] + r2[2][tid] + r2[3][tid]) * LOG2E;
  }
}

// ---------------- Kernel B: fully-fused masked-softmax + P@h + 1/Z + ELU
// 256 blocks x 1024 threads (16 waves); block = 32 rows x ALL 8192 cols.
// Wave grid 2(row-halves) x 8(feat-groups of 32): halves LDS A-frag traffic
// vs 1x16. In-loop global reads are mask (8 MB, L2/L3) + s2 + hT (4 MB, L2)
// only — NO HBM stream in the loop (adj pre-packed by gat_adjpack).
__global__ __launch_bounds__(1024, 4) void gat_attn_full(
    const unsigned* __restrict__ mask32, const unsigned short* __restrict__ hT,
    const float* __restrict__ s1, const float* __restrict__ s2,
    float* __restrict__ out) {
  const int bid = blockIdx.x;  // 0..255
  const int row0 = bid * 32;
  const int tid = threadIdx.x;
  const int wave = tid >> 6, lane = tid & 63;
  const int ln16 = lane & 15, quad = lane >> 4;
  const int wr = wave >> 3;   // 0..1  row half
  const int wc = wave & 7;    // 0..7  feature group (32 feats)

  __shared__ __align__(16) unsigned short P[2][32][72];  // double-buffered, +8 pad
  __shared__ float Zred[32][32];
  __shared__ float wred[16];
  __shared__ float Zinv[32];

  // ---- block-local global max of s2 (32 KB, L2-hot; bound for exp range)
  float m = -1e30f;
  for (int i = tid; i < 8192; i += 1024) m = fmaxf(m, s2[i]);
#pragma unroll
  for (int off = 32; off > 0; off >>= 1) m = fmaxf(m, __shfl_down(m, off));
  if (lane == 0) wred[wave] = m;
  __syncthreads();
  float s2m = wred[0];
#pragma unroll
  for (int wv = 1; wv < 16; ++wv) s2m = fmaxf(s2m, wred[wv]);

  const int r = tid >> 5;   // 0..31  producer row
  const int cg = tid & 31;  // 0..31  producer col-group (2 cols)
  const float s1r = s1[row0 + r];
  const float tmv = s1r + s2m;
  const float mr = tmv >= 0.f ? tmv : LRALPHA * tmv;  // >= row max of lrelu

  // mask: row-major uint32 words; window jt covers words [jt*2, jt*2+1]
  const unsigned* mrow = mask32 + (size_t)(row0 + r) * 256 + (cg >> 4);
  const int msh = (cg & 15) * 2;
  const float* s2p = s2 + cg * 2;
  // hT row base for this wave's features (ni selects +16)
  const unsigned short* hTw0 = hT + (size_t)(wc * 32 + ln16) * 8192 + quad * 8;
  const unsigned short* hTw1 = hTw0 + (size_t)16 * 8192;

  frag_cd acc[2];
  const frag_cd fz = {0.f, 0.f, 0.f, 0.f};
  acc[0] = fz; acc[1] = fz;

  float zloc = 0.f;
  const int NIT = 128;

  // preamble: w(0) -> P[0]; prefetch mask/s2 for jt=1; hT frags for jt=0
  {
    unsigned mw = mrow[0];
    fv2 cv = *(const fv2*)s2p;
    *(unsigned*)&P[0][r][cg * 2] = make_w2(mw >> msh, cv, s1r, mr, zloc);
  }
  unsigned pm = mrow[2];                 // window 1
  fv2 pv = *(const fv2*)(s2p + 64);
  frag_ab bfC[2][2];
#pragma unroll
  for (int kk = 0; kk < 2; ++kk) {
    bfC[kk][0] = *(const frag_ab*)(hTw0 + kk * 32);
    bfC[kk][1] = *(const frag_ab*)(hTw1 + kk * 32);
  }
  block_sync_lds();

  for (int jt = 0; jt < NIT; ++jt) {
    const int cur = jt & 1, nxt = cur ^ 1;

    // hT B-frags for NEXT iter — issued a full iteration before use
    frag_ab bfN[2][2];
    if (jt + 1 < NIT) {
      const size_t jn = (size_t)(jt + 1) * 64;
#pragma unroll
      for (int kk = 0; kk < 2; ++kk) {
        bfN[kk][0] = *(const frag_ab*)(hTw0 + jn + kk * 32);
        bfN[kk][1] = *(const frag_ab*)(hTw1 + jn + kk * 32);
      }
    }

    // prefetch mask/s2 for jt+2 (L2/L3-resident)
    unsigned pm2 = 0; fv2 pv2;
    if (jt + 2 < NIT) {
      pm2 = mrow[(jt + 2) * 2];
      pv2 = *(const fv2*)(s2p + (jt + 2) * 64);
    }

    // compute w(jt+1) -> P[nxt] (overlaps MFMA of jt; barrier-safe with dbuf)
    if (jt + 1 < NIT) {
      *(unsigned*)&P[nxt][r][cg * 2] = make_w2(pm >> msh, pv, s1r, mr, zloc);
    }

    // A-fragments from P[cur] (this wave's 16-row half only) + MFMA
    {
      frag_ab af0 = *(const frag_ab*)&P[cur][wr * 16 + ln16][quad * 8];       // kk=0
      acc[0] = __builtin_amdgcn_mfma_f32_16x16x32_bf16(af0, bfC[0][0], acc[0], 0, 0, 0);
      acc[1] = __builtin_amdgcn_mfma_f32_16x16x32_bf16(af0, bfC[0][1], acc[1], 0, 0, 0);
      frag_ab af1 = *(const frag_ab*)&P[cur][wr * 16 + ln16][32 + quad * 8];  // kk=1
      acc[0] = __builtin_amdgcn_mfma_f32_16x16x32_bf16(af1, bfC[1][0], acc[0], 0, 0, 0);
      acc[1] = __builtin_amdgcn_mfma_f32_16x16x32_bf16(af1, bfC[1][1], acc[1], 0, 0, 0);
    }
    block_sync_lds();
#pragma unroll
    for (int kk = 0; kk < 2; ++kk) {
      bfC[kk][0] = bfN[kk][0]; bfC[kk][1] = bfN[kk][1];
    }
    pm = pm2; pv = pv2;
  }

  // ---- Z reduce (full row is in-block) -> 1/Z
  Zred[r][cg] = zloc;
  __syncthreads();
  if (tid < 32) {
    float z = 0.f;
#pragma unroll
    for (int q = 0; q < 32; ++q) z += Zred[tid][q];
    Zinv[tid] = 1.f / z;
  }
  __syncthreads();

  // ---- epilogue: divide, elu, store output directly
  // C/D layout: col(feature)=lane&15, row=quad*4+reg; row half = wr*16
  float* outb = out + (size_t)row0 * 256;
  const int f0 = wc * 32 + ln16;
#pragma unroll
  for (int ni = 0; ni < 2; ++ni) {
#pragma unroll
    for (int reg = 0; reg < 4; ++reg) {
      const int grow = wr * 16 + quad * 4 + reg;
      const float vv = acc[ni][reg] * Zinv[grow];
      const float o = vv > 0.f ? vv : expm1f(vv);
      __builtin_nontemporal_store(o, outb + (size_t)grow * 256 + f0 + ni * 16);
    }
  }
}

extern "C" void kernel_launch(void* const* d_in, const int* in_sizes, int n_in,
                              void* d_out, int out_size, void* d_ws, size_t ws_size,
                              hipStream_t stream) {
  const float* X = (const float*)d_in[0];
  const int* adj = (const int*)d_in[1];
  const float* W = (const float*)d_in[2];
  const float* avec = (const float*)d_in[3];
  float* out = (float*)d_out;

  float* wsf = (float*)d_ws;
  float* s1 = wsf;                                        // 8192 floats
  float* s2 = wsf + 8192;                                 // 8192 floats
  unsigned short* hT = (unsigned short*)(wsf + 16384);    // 4 MB (1,048,576 floats)
  unsigned long long* mask = (unsigned long long*)(wsf + 16384 + 1048576);  // 8 MB

  hipLaunchKernelGGL(gat_adjpack, dim3(2048), dim3(256), 0, stream, adj, mask);
  hipLaunchKernelGGL(gat_hproj, dim3(512), dim3(256), 0, stream, X, W, avec, s1, s2, hT);
  hipLaunchKernelGGL(gat_attn_full, dim3(256), dim3(1024), 0, stream,
                     (const unsigned*)mask, hT, s1, s2, out);
}

// Round 7
// 592.875 us; speedup vs baseline: 1.1178x; 1.1178x over previous
//
#include <hip/hip_runtime.h>
#include <hip/hip_bf16.h>

#define LRALPHA 0.2f
#define LOG2E 1.4426950408889634f

typedef __attribute__((ext_vector_type(8))) short frag_ab;    // 8 x bf16
typedef __attribute__((ext_vector_type(16))) float f32x16;    // 32x32 acc
typedef float fv4 __attribute__((ext_vector_type(4)));
typedef unsigned int uv4 __attribute__((ext_vector_type(4)));

static __device__ __forceinline__ unsigned short f2bf(float f) {
  __hip_bfloat16 b = __float2bfloat16(f);
  unsigned short u;
  __builtin_memcpy(&u, &b, 2);
  return u;
}

#if __has_builtin(__builtin_amdgcn_exp2f)
#define EXP2F(x) __builtin_amdgcn_exp2f(x)
#else
#define EXP2F(x) exp2f(x)
#endif

// 2 x f32 -> packed 2 x bf16 (RNE), gfx950-native
static __device__ __forceinline__ unsigned cvt_pk_bf16(float lo, float hi) {
  unsigned r;
  asm("v_cvt_pk_bf16_f32 %0, %1, %2" : "=v"(r) : "v"(lo), "v"(hi));
  return r;
}

// 8 w-values -> one in-register A-fragment for mfma_f32_32x32x16_bf16.
// Lane l feeds rows (l&31), k = (l>>5)*8 + e. Masked-out: arg=-200 -> exp2=0.
static __device__ __forceinline__ frag_ab make_w8(unsigned mb, fv4 sa, fv4 sb,
                                                  float s1r, float mr, float& zloc) {
  float w[8];
#pragma unroll
  for (int e = 0; e < 8; ++e) {
    const float sv = (e < 4) ? sa[e] : sb[e - 4];
    float ee = s1r + sv;                    // log2 units
    ee = fmaxf(ee, LRALPHA * ee);           // leakyrelu (slope<1)
    const float arg = ((mb >> e) & 1u) ? (ee - mr) : -200.f;  // exp2(-200)=+0
    const float ww = EXP2F(arg);
    zloc += ww;
    w[e] = ww;
  }
  uv4 u;
  u[0] = cvt_pk_bf16(w[0], w[1]);
  u[1] = cvt_pk_bf16(w[2], w[3]);
  u[2] = cvt_pk_bf16(w[4], w[5]);
  u[3] = cvt_pk_bf16(w[6], w[7]);
  frag_ab a;
  __builtin_memcpy(&a, &u, 16);
  return a;
}

// ---------------- Kernel 0: adj (int32, 256 MB) -> bitmask (8 MB)
__global__ __launch_bounds__(256) void gat_adjpack(
    const int* __restrict__ adj, unsigned long long* __restrict__ mask) {
  const int lane = threadIdx.x & 63;
  const int wid = (blockIdx.x * 256 + threadIdx.x) >> 6;  // 0..8191
  const int NW = (2048 * 256) >> 6;                       // 8192
  const int NWORDS = (8192 * 8192) / 64;                  // 1,048,576
  for (int w0 = wid * 4; w0 < NWORDS; w0 += NW * 4) {
    int v0 = __builtin_nontemporal_load(&adj[(size_t)(w0 + 0) * 64 + lane]);
    int v1 = __builtin_nontemporal_load(&adj[(size_t)(w0 + 1) * 64 + lane]);
    int v2 = __builtin_nontemporal_load(&adj[(size_t)(w0 + 2) * 64 + lane]);
    int v3 = __builtin_nontemporal_load(&adj[(size_t)(w0 + 3) * 64 + lane]);
    unsigned long long m0 = __ballot(v0 > 0);
    unsigned long long m1 = __ballot(v1 > 0);
    unsigned long long m2 = __ballot(v2 > 0);
    unsigned long long m3 = __ballot(v3 > 0);
    if (lane == 0) {
      mask[w0 + 0] = m0; mask[w0 + 1] = m1;
      mask[w0 + 2] = m2; mask[w0 + 3] = m3;
    }
  }
}

// ---------------- Kernel A: h = X@W (fp32), s1/s2 (pre-scaled by log2 e), hT = bf16(h)^T
__global__ __launch_bounds__(256, 4) void gat_hproj(
    const float* __restrict__ X, const float* __restrict__ W,
    const float* __restrict__ avec,
    float* __restrict__ s1, float* __restrict__ s2,
    unsigned short* __restrict__ hT) {
  const int tid = threadIdx.x;
  const int row0 = blockIdx.x * 16;
  const float* Xb = X + (size_t)row0 * 256;
  const int c = tid;

  float acc[16];
#pragma unroll
  for (int r = 0; r < 16; ++r) acc[r] = 0.f;

  for (int k = 0; k < 256; k += 4) {
    const float w0 = W[(k + 0) * 256 + c];
    const float w1 = W[(k + 1) * 256 + c];
    const float w2 = W[(k + 2) * 256 + c];
    const float w3 = W[(k + 3) * 256 + c];
#pragma unroll
    for (int r = 0; r < 16; ++r) {
      acc[r] = fmaf(Xb[r * 256 + k + 0], w0, acc[r]);
      acc[r] = fmaf(Xb[r * 256 + k + 1], w1, acc[r]);
      acc[r] = fmaf(Xb[r * 256 + k + 2], w2, acc[r]);
      acc[r] = fmaf(Xb[r * 256 + k + 3], w3, acc[r]);
    }
  }

  alignas(16) unsigned short hu[16];
#pragma unroll
  for (int r = 0; r < 16; ++r) hu[r] = f2bf(acc[r]);
  uv4* hdst = (uv4*)(hT + (size_t)c * 8192 + row0);
  hdst[0] = *(const uv4*)&hu[0];
  hdst[1] = *(const uv4*)&hu[8];

  const float a1c = avec[c];
  const float a2c = avec[256 + c];
  const int lane = tid & 63, wave = tid >> 6;
  __shared__ float r1[4][16], r2[4][16];
#pragma unroll
  for (int r = 0; r < 16; ++r) {
    float v1 = acc[r] * a1c;
    float v2 = acc[r] * a2c;
#pragma unroll
    for (int off = 32; off > 0; off >>= 1) {
      v1 += __shfl_down(v1, off);
      v2 += __shfl_down(v2, off);
    }
    if (lane == 0) { r1[wave][r] = v1; r2[wave][r] = v2; }
  }
  __syncthreads();
  if (tid < 16) {
    s1[row0 + tid] = (r1[0][tid] + r1[1][tid] + r1[2][tid] + r1[3][tid]) * LOG2E;
    s2[row0 + tid] = (r2[0][tid] + r2[1][tid] + r2[2][tid] + r2[3][tid]) * LOG2E;
  }
}

// ---------------- Kernel B: barrier-free masked-softmax + P@h partials
// Grid 1024 = 256 rowgroups (32 rows) x 4 j-splits. Block 256 thr = 4 waves:
// wave = (jg = w>>1) x (fg = w&1). Wave tile: 32 rows x 128 feats x 1024 j.
// A-fragments computed IN REGISTERS per lane (layout: row=l&31, k=(l>>5)*8+e)
// -> no P LDS, no barriers in the main loop. hT B-frags from L2 (4 MB, resident).
__global__ __launch_bounds__(256, 3) void gat_attn_part(
    const unsigned char* __restrict__ maskB, const unsigned short* __restrict__ hT,
    const float* __restrict__ s1, const float* __restrict__ s2,
    float* __restrict__ pacc, float* __restrict__ pZ) {
  const int bid = blockIdx.x;
  const int rowg = bid >> 2, js = bid & 3;
  const int row0 = rowg * 32;
  const int tid = threadIdx.x;
  const int wave = tid >> 6, lane = tid & 63;
  const int fg = wave & 1, jg = wave >> 1;
  const int ln32 = lane & 31, half = lane >> 5;

  __shared__ float wred[4];
  __shared__ float accL[32][260];  // +4 pad
  __shared__ float zL[32];

  // block-local global max of s2 (bound for exp range)
  float m = -1e30f;
  for (int i = tid; i < 8192; i += 256) m = fmaxf(m, s2[i]);
#pragma unroll
  for (int off = 32; off > 0; off >>= 1) m = fmaxf(m, __shfl_down(m, off));
  if (lane == 0) wred[wave] = m;
  __syncthreads();
  const float s2m = fmaxf(fmaxf(wred[0], wred[1]), fmaxf(wred[2], wred[3]));

  const float s1r = s1[row0 + ln32];                  // this lane's A-row
  const float tmv = s1r + s2m;
  const float mr = tmv >= 0.f ? tmv : LRALPHA * tmv;  // >= row max of lrelu

  const int jbase = (js * 2 + jg) * 1024;             // this wave's j-range
  const unsigned char* mrow = maskB + (size_t)(row0 + ln32) * 1024 + half;
  const unsigned short* hTl = hT + (size_t)(fg * 128 + ln32) * 8192 + half * 8;

  f32x16 acc[4];
#pragma unroll
  for (int ni = 0; ni < 4; ++ni) acc[ni] = (f32x16)(0.f);
  float zloc = 0.f;

  struct LSet { frag_ab B[4]; unsigned mb; fv4 sa, sb; };
  LSet Sa, Sb;

#define LOADSET(S, T)                                                       \
  {                                                                         \
    const int j0_ = jbase + (T) * 16;                                       \
    (S).mb = mrow[j0_ >> 3];                                                \
    const float* sp_ = s2 + j0_ + half * 8;                                 \
    (S).sa = *(const fv4*)sp_;                                              \
    (S).sb = *(const fv4*)(sp_ + 4);                                        \
    _Pragma("unroll")                                                       \
    for (int ni = 0; ni < 4; ++ni)                                          \
      (S).B[ni] = *(const frag_ab*)(hTl + (size_t)ni * 32 * 8192 + j0_);    \
  }

#define USESET(S)                                                           \
  {                                                                         \
    frag_ab A_ = make_w8((S).mb, (S).sa, (S).sb, s1r, mr, zloc);            \
    _Pragma("unroll")                                                       \
    for (int ni = 0; ni < 4; ++ni)                                          \
      acc[ni] = __builtin_amdgcn_mfma_f32_32x32x16_bf16(A_, (S).B[ni],      \
                                                        acc[ni], 0, 0, 0);  \
  }

  LOADSET(Sa, 0);
  for (int t = 0; t < 64; t += 2) {
    LOADSET(Sb, t + 1);
    USESET(Sa);
    LOADSET(Sa, t + 2);  // t=62 -> window 64: benign in-workspace over-read
    USESET(Sb);
  }
#undef LOADSET
#undef USESET

  // Z: lane l covers row (l&31), k-half (l>>5); combine halves
  float zrow = zloc + __shfl_xor(zloc, 32);

  // jg-pair combine through LDS (one barrier), then write partial js
  // C/D layout (32x32): col(f-offset)=lane&31, row=(reg&3)+8*(reg>>2)+4*(lane>>5)
  if (jg == 0) {
#pragma unroll
    for (int ni = 0; ni < 4; ++ni)
#pragma unroll
      for (int reg = 0; reg < 16; ++reg) {
        const int grow = (reg & 3) + 8 * (reg >> 2) + 4 * half;
        accL[grow][fg * 128 + ni * 32 + ln32] = acc[ni][reg];
      }
    if (fg == 0 && lane < 32) zL[lane] = zrow;
  }
  __syncthreads();
  if (jg == 1) {
    float* paccb = pacc + ((size_t)js * 8192 + row0) * 256;
#pragma unroll
    for (int ni = 0; ni < 4; ++ni)
#pragma unroll
      for (int reg = 0; reg < 16; ++reg) {
        const int grow = (reg & 3) + 8 * (reg >> 2) + 4 * half;
        const int f = fg * 128 + ni * 32 + ln32;
        __builtin_nontemporal_store(acc[ni][reg] + accL[grow][f],
                                    paccb + (size_t)grow * 256 + f);
      }
    if (fg == 0 && lane < 32)
      pZ[js * 8192 + row0 + lane] = zrow + zL[lane];
  }
}

// ---------------- Kernel D: combine 4 j-split partials, divide by Z, elu
__global__ __launch_bounds__(256) void gat_combine(
    const float* __restrict__ pacc, const float* __restrict__ pZ,
    float* __restrict__ out) {
  const int idx = blockIdx.x * 256 + threadIdx.x;  // float4 index, 524288 total
  const int row = idx >> 6;
  const float z = pZ[row] + pZ[8192 + row] + pZ[16384 + row] + pZ[24576 + row];
  const float invz = 1.f / z;
  const size_t PSTRIDE = (size_t)8192 * 256;
  const fv4 n0 = *(const fv4*)(pacc + (size_t)idx * 4);
  const fv4 n1 = *(const fv4*)(pacc + PSTRIDE + (size_t)idx * 4);
  const fv4 n2 = *(const fv4*)(pacc + 2 * PSTRIDE + (size_t)idx * 4);
  const fv4 n3 = *(const fv4*)(pacc + 3 * PSTRIDE + (size_t)idx * 4);
  fv4 o;
#pragma unroll
  for (int e = 0; e < 4; ++e) {
    const float vsum = (n0[e] + n1[e]) + (n2[e] + n3[e]);
    const float vv = vsum * invz;
    o[e] = vv > 0.f ? vv : expm1f(vv);
  }
  *(fv4*)(out + (size_t)idx * 4) = o;
}

extern "C" void kernel_launch(void* const* d_in, const int* in_sizes, int n_in,
                              void* d_out, int out_size, void* d_ws, size_t ws_size,
                              hipStream_t stream) {
  const float* X = (const float*)d_in[0];
  const int* adj = (const int*)d_in[1];
  const float* W = (const float*)d_in[2];
  const float* avec = (const float*)d_in[3];
  float* out = (float*)d_out;

  float* wsf = (float*)d_ws;
  float* s1 = wsf;                                   // 8192
  float* s2 = wsf + 8192;                            // 8192
  float* pZ = wsf + 16384;                           // 4*8192
  float* pacc = wsf + 49152;                         // 4*8192*256 = 8,388,608 floats
  unsigned short* hT = (unsigned short*)(wsf + 49152 + 8388608);      // 4 MB
  unsigned long long* mask =
      (unsigned long long*)(wsf + 49152 + 8388608 + 2097152);         // 8 MB

  hipLaunchKernelGGL(gat_adjpack, dim3(2048), dim3(256), 0, stream, adj, mask);
  hipLaunchKernelGGL(gat_hproj, dim3(512), dim3(256), 0, stream, X, W, avec, s1, s2, hT);
  hipLaunchKernelGGL(gat_attn_part, dim3(1024), dim3(256), 0, stream,
                     (const unsigned char*)mask, hT, s1, s2, pacc, pZ);
  hipLaunchKernelGGL(gat_combine, dim3(2048), dim3(256), 0, stream, pacc, pZ, out);
}